// Round 3
// baseline (348.153 us; speedup 1.0000x reference)
//
#include <hip/hip_runtime.h>
#include <math.h>

namespace {
constexpr int S  = 256;
constexpr int NT = 256;
constexpr float SCALE = 0.0625f;  // 1/sqrt(256)
}

typedef __bf16 bf16x4 __attribute__((ext_vector_type(4)));
typedef __bf16 bf16x8 __attribute__((ext_vector_type(8)));
typedef float  f32x4  __attribute__((ext_vector_type(4)));

#define MFMA(a, b, c) __builtin_amdgcn_mfma_f32_16x16x32_bf16((a), (b), (c), 0, 0, 0)

// ============ prep: V^T 3-way bf16 split: vth/vtl/vtll[bh][d][t] ============
__global__ __launch_bounds__(NT) void vsplit_kernel(
    const float* __restrict__ v,
    __bf16* __restrict__ vth, __bf16* __restrict__ vtl, __bf16* __restrict__ vtll)
{
    __shared__ float tile[64][65];
    const int tileIdx = blockIdx.x & 15;
    const int bh      = blockIdx.x >> 4;
    const int ti = (tileIdx >> 2) * 64;   // t-origin
    const int tj = (tileIdx & 3) * 64;    // d-origin
    const float* vb = v + (size_t)bh * S * S;

    const int c  = threadIdx.x & 63;
    const int r4 = threadIdx.x >> 6;

    #pragma unroll
    for (int rr = 0; rr < 64; rr += 4)
        tile[rr + r4][c] = vb[(size_t)(ti + rr + r4) * S + tj + c];
    __syncthreads();

    const size_t ob = (size_t)bh * S * S;
    #pragma unroll
    for (int rr = 0; rr < 64; rr += 4) {
        const float x = tile[c][rr + r4];            // v[t=ti+c][d=tj+rr+r4]
        const __bf16 hi = (__bf16)x;
        const float  hf = (float)hi;
        const __bf16 lo = (__bf16)(x - hf);
        const float  lf = (float)lo;
        const __bf16 ll = (__bf16)(x - hf - lf);
        const size_t oi = ob + (size_t)(tj + rr + r4) * S + ti + c;
        vth[oi] = hi; vtl[oi] = lo; vtll[oi] = ll;
    }
}

// ============ main fused MFMA kernel: 64 rows per block, 4 waves ============
__global__ __launch_bounds__(NT) void attn_mfma_kernel(
    const float* __restrict__ q, const float* __restrict__ k,
    const float* __restrict__ mask,
    const __bf16* __restrict__ vth, const __bf16* __restrict__ vtl,
    const __bf16* __restrict__ vtll,
    float* __restrict__ out, int H, int swz)
{
    // A tiles (r hi/lo, then P) : [64][256] bf16, XOR-swizzled rows
    __shared__ __align__(16) __bf16 a_hi[64 * 256];
    __shared__ __align__(16) __bf16 a_lo[64 * 256];
    // B tiles: [256][32] bf16, padded to 40 elems/row (80 B) -> conflict-free
    __shared__ __align__(16) __bf16 b0[256 * 40];
    __shared__ __align__(16) __bf16 b1[256 * 40];
    __shared__ __align__(16) __bf16 b2[256 * 40];
    // mask chunk [64][32] (pad 40)
    __shared__ __align__(16) __bf16 mh[64 * 40];

    const int tid = threadIdx.x;
    const int w   = tid >> 6;
    const int l   = tid & 63;
    const int l15 = l & 15;
    const int l4  = l >> 4;

    int L = blockIdx.x;
    if (swz) L = (blockIdx.x & 7) * ((int)gridDim.x >> 3) + (blockIdx.x >> 3);
    const int bh = L >> 2;
    const int s0 = (L & 3) << 6;
    const int h  = bh % H;

    const size_t hb = (size_t)bh << 16;
    const float* qb  = q    + hb;
    const float* kb  = k    + hb;
    const float* mb  = mask + ((size_t)h << 16);
    const __bf16* vhb  = vth  + hb;
    const __bf16* vlb  = vtl  + hb;
    const __bf16* vllb = vtll + hb;

    // ---- preload Q fragments (hi/lo splits) for all 8 k-chunks ----
    bf16x8 qh[8], ql[8];
    {
        const float* qr = qb + (size_t)(s0 + 16 * w + l15) * S;
        #pragma unroll
        for (int kc = 0; kc < 8; ++kc) {
            const float4 f0 = *(const float4*)&qr[kc * 32 + l4 * 8];
            const float4 f1 = *(const float4*)&qr[kc * 32 + l4 * 8 + 4];
            const float xs[8] = {f0.x, f0.y, f0.z, f0.w, f1.x, f1.y, f1.z, f1.w};
            bf16x8 hv, lv;
            #pragma unroll
            for (int e = 0; e < 8; ++e) {
                const __bf16 hi = (__bf16)xs[e];
                hv[e] = hi;
                lv[e] = (__bf16)(xs[e] - (float)hi);
            }
            qh[kc] = hv; ql[kc] = lv;
        }
    }

    // ---- stage 1a: r-frags = scale * Q K^T (3-pass split bf16 MFMA) ----
    f32x4 acc1[16];
    #pragma unroll
    for (int j = 0; j < 16; ++j) acc1[j] = (f32x4){0.f, 0.f, 0.f, 0.f};

    for (int kc = 0; kc < 8; ++kc) {
        #pragma unroll
        for (int pass = 0; pass < 8; ++pass) {
            const int row = pass * 32 + (tid >> 3);
            const int sub = tid & 7;
            const float4 f = *(const float4*)&kb[(size_t)row * S + kc * 32 + sub * 4];
            const float xs[4] = {f.x, f.y, f.z, f.w};
            bf16x4 hv, lv;
            #pragma unroll
            for (int e = 0; e < 4; ++e) {
                const __bf16 hi = (__bf16)xs[e];
                hv[e] = hi;
                lv[e] = (__bf16)(xs[e] - (float)hi);
            }
            *(bf16x4*)&b0[row * 40 + sub * 4] = hv;
            *(bf16x4*)&b1[row * 40 + sub * 4] = lv;
        }
        __syncthreads();
        #pragma unroll
        for (int j = 0; j < 16; ++j) {
            const int bo = (j * 16 + l15) * 40 + l4 * 8;
            const bf16x8 kh_ = *(const bf16x8*)&b0[bo];
            const bf16x8 kl_ = *(const bf16x8*)&b1[bo];
            acc1[j] = MFMA(qh[kc], kh_, acc1[j]);
            acc1[j] = MFMA(qh[kc], kl_, acc1[j]);
            acc1[j] = MFMA(ql[kc], kh_, acc1[j]);
        }
        __syncthreads();
    }

    // ---- scale, split r into hi/lo, write to swizzled A-tiles ----
    #pragma unroll
    for (int j = 0; j < 16; ++j) {
        #pragma unroll
        for (int rr = 0; rr < 4; ++rr) {
            const int srow = 16 * w + l4 * 4 + rr;
            const int t    = j * 16 + l15;
            const float r  = acc1[j][rr] * SCALE;
            const __bf16 hi = (__bf16)r;
            const int idx = ((srow << 8) + t) ^ ((srow & 7) << 3);
            a_hi[idx] = hi;
            a_lo[idx] = (__bf16)(r - (float)hi);
        }
    }
    __syncthreads();

    // ---- merged sweep: acc2 = (mask + r) @ V  (6 passes) ----
    f32x4 acc2[16];
    #pragma unroll
    for (int j = 0; j < 16; ++j) acc2[j] = (f32x4){0.f, 0.f, 0.f, 0.f};

    for (int tc = 0; tc < 8; ++tc) {
        #pragma unroll
        for (int pass = 0; pass < 8; ++pass) {
            const int row = pass * 32 + (tid >> 3);
            const int sub = tid & 7;
            const size_t gi = (size_t)row * S + tc * 32 + sub * 4;
            *(bf16x4*)&b0[row * 40 + sub * 4] = *(const bf16x4*)&vhb[gi];
            *(bf16x4*)&b1[row * 40 + sub * 4] = *(const bf16x4*)&vlb[gi];
            *(bf16x4*)&b2[row * 40 + sub * 4] = *(const bf16x4*)&vllb[gi];
        }
        #pragma unroll
        for (int pass = 0; pass < 2; ++pass) {
            const int row = pass * 32 + (tid >> 3);
            const int sub = tid & 7;
            const float4 f = *(const float4*)&mb[(size_t)(s0 + row) * S + tc * 32 + sub * 4];
            bf16x4 mv;
            mv[0] = (__bf16)f.x; mv[1] = (__bf16)f.y;
            mv[2] = (__bf16)f.z; mv[3] = (__bf16)f.w;
            *(bf16x4*)&mh[row * 40 + sub * 4] = mv;
        }
        __syncthreads();
        const int arow = 16 * w + l15;
        const int ab = ((arow << 8) + tc * 32 + l4 * 8) ^ ((arow & 7) << 3);
        const bf16x8 arh = *(const bf16x8*)&a_hi[ab];
        const bf16x8 arl = *(const bf16x8*)&a_lo[ab];
        const bf16x8 amh = *(const bf16x8*)&mh[arow * 40 + l4 * 8];
        #pragma unroll
        for (int j = 0; j < 16; ++j) {
            const int bo = (j * 16 + l15) * 40 + l4 * 8;
            const bf16x8 bvh  = *(const bf16x8*)&b0[bo];
            const bf16x8 bvl  = *(const bf16x8*)&b1[bo];
            const bf16x8 bvll = *(const bf16x8*)&b2[bo];
            acc2[j] = MFMA(amh, bvh,  acc2[j]);
            acc2[j] = MFMA(amh, bvl,  acc2[j]);
            acc2[j] = MFMA(amh, bvll, acc2[j]);
            acc2[j] = MFMA(arh, bvh,  acc2[j]);
            acc2[j] = MFMA(arh, bvl,  acc2[j]);
            acc2[j] = MFMA(arl, bvh,  acc2[j]);
        }
        __syncthreads();
    }

    // ---- masked fill + row softmax (in-register, per quarter-wave) ----
    #pragma unroll
    for (int rr = 0; rr < 4; ++rr) {
        const int srow = 16 * w + l4 * 4 + rr;
        const float* mrow = mb + (size_t)(s0 + srow) * S;
        float mx = -3.4e38f;
        #pragma unroll
        for (int j = 0; j < 16; ++j) {
            const float mval = mrow[j * 16 + l15];
            const float a = (mval == 0.0f) ? -1e9f : acc2[j][rr];
            acc2[j][rr] = a;
            mx = fmaxf(mx, a);
        }
        #pragma unroll
        for (int off = 1; off < 16; off <<= 1)
            mx = fmaxf(mx, __shfl_xor(mx, off, 64));
        float sm = 0.f;
        #pragma unroll
        for (int j = 0; j < 16; ++j) {
            const float e = __expf(acc2[j][rr] - mx);
            acc2[j][rr] = e;
            sm += e;
        }
        #pragma unroll
        for (int off = 1; off < 16; off <<= 1)
            sm += __shfl_xor(sm, off, 64);
        const float inv = 1.0f / sm;
        #pragma unroll
        for (int j = 0; j < 16; ++j) {
            const int t = j * 16 + l15;
            const int idx = ((srow << 8) + t) ^ ((srow & 7) << 3);
            a_hi[idx] = (__bf16)(acc2[j][rr] * inv);   // P (own rows only)
        }
    }

    // ---- stage 2: out = P @ V  (ph*vh + ph*vl) ----
    f32x4 acc3[16];
    #pragma unroll
    for (int j = 0; j < 16; ++j) acc3[j] = (f32x4){0.f, 0.f, 0.f, 0.f};

    for (int tc = 0; tc < 8; ++tc) {
        #pragma unroll
        for (int pass = 0; pass < 8; ++pass) {
            const int row = pass * 32 + (tid >> 3);
            const int sub = tid & 7;
            const size_t gi = (size_t)row * S + tc * 32 + sub * 4;
            *(bf16x4*)&b0[row * 40 + sub * 4] = *(const bf16x4*)&vhb[gi];
            *(bf16x4*)&b1[row * 40 + sub * 4] = *(const bf16x4*)&vlb[gi];
        }
        __syncthreads();
        const int arow = 16 * w + l15;
        const int ab = ((arow << 8) + tc * 32 + l4 * 8) ^ ((arow & 7) << 3);
        const bf16x8 aph = *(const bf16x8*)&a_hi[ab];
        #pragma unroll
        for (int j = 0; j < 16; ++j) {
            const int bo = (j * 16 + l15) * 40 + l4 * 8;
            const bf16x8 bvh = *(const bf16x8*)&b0[bo];
            const bf16x8 bvl = *(const bf16x8*)&b1[bo];
            acc3[j] = MFMA(aph, bvh, acc3[j]);
            acc3[j] = MFMA(aph, bvl, acc3[j]);
        }
        __syncthreads();
    }

    float* ob = out + hb + (size_t)s0 * S;
    #pragma unroll
    for (int j = 0; j < 16; ++j) {
        #pragma unroll
        for (int rr = 0; rr < 4; ++rr)
            ob[(size_t)(16 * w + l4 * 4 + rr) * S + j * 16 + l15] = acc3[j][rr];
    }
}

// ================= fallback: round-2 fp32 path (verified) =================
__global__ __launch_bounds__(NT) void transpose_k_kernel(
    const float* __restrict__ k, float* __restrict__ kt)
{
    __shared__ float tile[64][65];
    const int tileIdx = blockIdx.x & 15;
    const int bh      = blockIdx.x >> 4;
    const int ti = (tileIdx >> 2) * 64;
    const int tj = (tileIdx & 3) * 64;
    const float* kb = k  + (size_t)bh * S * S;
    float*      ktb = kt + (size_t)bh * S * S;
    const int c  = threadIdx.x & 63;
    const int r4 = threadIdx.x >> 6;
    #pragma unroll
    for (int rr = 0; rr < 64; rr += 4)
        tile[rr + r4][c] = kb[(size_t)(ti + rr + r4) * S + tj + c];
    __syncthreads();
    #pragma unroll
    for (int rr = 0; rr < 64; rr += 4)
        ktb[(size_t)(tj + rr + r4) * S + ti + c] = tile[c][rr + r4];
}

template <int RPB>
__global__ __launch_bounds__(NT) void fused_attn_rpb(
    const float* __restrict__ q, const float* __restrict__ kt,
    const float* __restrict__ v, const float* __restrict__ mask,
    float* __restrict__ out, int nbh, int H, int swizzle)
{
    __shared__ float qT[S][RPB];
    __shared__ float sT[S][RPB];
    __shared__ float redbuf[4][RPB];

    const int tid = threadIdx.x;
    constexpr int NRB = S / RPB;
    int bh, rb;
    if (swizzle) {
        const int xcd  = blockIdx.x & 7;
        const int slot = blockIdx.x >> 3;
        const int hpx  = nbh >> 3;
        bh = xcd * hpx + (slot % hpx);
        rb = slot / hpx;
    } else {
        bh = blockIdx.x / NRB;
        rb = blockIdx.x % NRB;
    }
    const int h  = bh % H;
    const int s0 = rb * RPB;

    const float* qb  = q    + (size_t)bh * S * S;
    const float* ktb = kt   + (size_t)bh * S * S;
    const float* vb  = v    + (size_t)bh * S * S;
    const float* mb  = mask + (size_t)h  * S * S + (size_t)s0 * S;
    float*       ob  = out  + (size_t)bh * S * S + (size_t)s0 * S;

    #pragma unroll
    for (int si = 0; si < RPB; ++si)
        qT[tid][si] = qb[(size_t)(s0 + si) * S + tid];
    __syncthreads();

    {
        float acc[RPB];
        #pragma unroll
        for (int si = 0; si < RPB; ++si) acc[si] = 0.f;
        #pragma unroll 4
        for (int i = 0; i < S; ++i) {
            const float kv = ktb[(size_t)i * S + tid];
            #pragma unroll
            for (int si4 = 0; si4 < RPB; si4 += 4) {
                const float4 qa = *reinterpret_cast<const float4*>(&qT[i][si4]);
                acc[si4+0] = fmaf(qa.x, kv, acc[si4+0]);
                acc[si4+1] = fmaf(qa.y, kv, acc[si4+1]);
                acc[si4+2] = fmaf(qa.z, kv, acc[si4+2]);
                acc[si4+3] = fmaf(qa.w, kv, acc[si4+3]);
            }
        }
        #pragma unroll
        for (int si4 = 0; si4 < RPB; si4 += 4) {
            float4 t4;
            t4.x = fmaf(acc[si4+0], SCALE, mb[(size_t)(si4+0)*S + tid]);
            t4.y = fmaf(acc[si4+1], SCALE, mb[(size_t)(si4+1)*S + tid]);
            t4.z = fmaf(acc[si4+2], SCALE, mb[(size_t)(si4+2)*S + tid]);
            t4.w = fmaf(acc[si4+3], SCALE, mb[(size_t)(si4+3)*S + tid]);
            *reinterpret_cast<float4*>(&sT[tid][si4]) = t4;
        }
    }
    __syncthreads();

    float a1[RPB];
    #pragma unroll
    for (int si = 0; si < RPB; ++si) a1[si] = 0.f;
    #pragma unroll 2
    for (int t = 0; t < S; ++t) {
        const float vv = vb[(size_t)t * S + tid];
        #pragma unroll
        for (int si4 = 0; si4 < RPB; si4 += 4) {
            const float4 pa = *reinterpret_cast<const float4*>(&sT[t][si4]);
            a1[si4+0] = fmaf(pa.x, vv, a1[si4+0]);
            a1[si4+1] = fmaf(pa.y, vv, a1[si4+1]);
            a1[si4+2] = fmaf(pa.z, vv, a1[si4+2]);
            a1[si4+3] = fmaf(pa.w, vv, a1[si4+3]);
        }
    }
    #pragma unroll
    for (int si = 0; si < RPB; ++si)
        if (mb[(size_t)si * S + tid] == 0.0f) a1[si] = -1e9f;

    const int lane = tid & 63;
    const int wv   = tid >> 6;
    #pragma unroll
    for (int si = 0; si < RPB; ++si) {
        float m = a1[si];
        #pragma unroll
        for (int off = 32; off > 0; off >>= 1)
            m = fmaxf(m, __shfl_down(m, off, 64));
        if (lane == 0) redbuf[wv][si] = m;
    }
    __syncthreads();
    float e[RPB];
    #pragma unroll
    for (int si = 0; si < RPB; ++si) {
        const float m = fmaxf(fmaxf(redbuf[0][si], redbuf[1][si]),
                              fmaxf(redbuf[2][si], redbuf[3][si]));
        e[si] = __expf(a1[si] - m);
    }
    __syncthreads();
    #pragma unroll
    for (int si = 0; si < RPB; ++si) {
        float sm = e[si];
        #pragma unroll
        for (int off = 32; off > 0; off >>= 1)
            sm += __shfl_down(sm, off, 64);
        if (lane == 0) redbuf[wv][si] = sm;
    }
    __syncthreads();
    #pragma unroll
    for (int si4 = 0; si4 < RPB; si4 += 4) {
        float4 t4;
        #pragma unroll
        for (int jj = 0; jj < 4; ++jj) {
            const int si = si4 + jj;
            const float sm = redbuf[0][si] + redbuf[1][si] +
                             redbuf[2][si] + redbuf[3][si];
            (&t4.x)[jj] = e[si] / sm;
        }
        *reinterpret_cast<float4*>(&sT[tid][si4]) = t4;
    }
    __syncthreads();

    float o[RPB];
    #pragma unroll
    for (int si = 0; si < RPB; ++si) o[si] = 0.f;
    #pragma unroll 2
    for (int t = 0; t < S; ++t) {
        const float vv = vb[(size_t)t * S + tid];
        #pragma unroll
        for (int si4 = 0; si4 < RPB; si4 += 4) {
            const float4 pa = *reinterpret_cast<const float4*>(&sT[t][si4]);
            o[si4+0] = fmaf(pa.x, vv, o[si4+0]);
            o[si4+1] = fmaf(pa.y, vv, o[si4+1]);
            o[si4+2] = fmaf(pa.z, vv, o[si4+2]);
            o[si4+3] = fmaf(pa.w, vv, o[si4+3]);
        }
    }
    #pragma unroll
    for (int si = 0; si < RPB; ++si)
        ob[(size_t)si * S + tid] = o[si];
}

extern "C" void kernel_launch(void* const* d_in, const int* in_sizes, int n_in,
                              void* d_out, int out_size, void* d_ws, size_t ws_size,
                              hipStream_t stream) {
    const float* q    = (const float*)d_in[0];
    const float* k    = (const float*)d_in[1];
    const float* v    = (const float*)d_in[2];
    const float* mask = (const float*)d_in[3];
    float* out = (float*)d_out;

    const int nbh = in_sizes[0] / (S * S);   // B*H
    const int H   = in_sizes[3] / (S * S);   // heads
    const size_t head_elems = (size_t)nbh * S * S;
    const size_t vsplit_bytes = head_elems * sizeof(__bf16) * 3;
    const size_t kt_bytes = head_elems * sizeof(float);

    if (ws_size >= vsplit_bytes && (nbh & 1) == 0) {
        __bf16* vth  = (__bf16*)d_ws;
        __bf16* vtl  = vth + head_elems;
        __bf16* vtll = vtl + head_elems;
        vsplit_kernel<<<dim3(nbh * 16), NT, 0, stream>>>(v, vth, vtl, vtll);
        const int nblk = nbh * 4;
        const int swz = (nblk % 8 == 0) ? 1 : 0;
        attn_mfma_kernel<<<dim3(nblk), NT, 0, stream>>>(
            q, k, mask, vth, vtl, vtll, out, H, swz);
    } else if (ws_size >= kt_bytes) {
        float* kt = (float*)d_ws;
        transpose_k_kernel<<<dim3(nbh * 16), NT, 0, stream>>>(k, kt);
        constexpr int RPB = 16;
        const int grid = nbh * (S / RPB);
        const int swz = (nbh % 8 == 0) ? 1 : 0;
        fused_attn_rpb<RPB><<<dim3(grid), NT, 0, stream>>>(
            q, kt, v, mask, out, nbh, H, swz);
    }
}

// Round 4
// 221.472 us; speedup vs baseline: 1.5720x; 1.5720x over previous
//
#include <hip/hip_runtime.h>
#include <math.h>

namespace {
constexpr int S  = 256;
constexpr int NT = 256;
constexpr float SCALE = 0.0625f;  // 1/sqrt(256)
}

typedef __bf16 bf16x4 __attribute__((ext_vector_type(4)));
typedef __bf16 bf16x8 __attribute__((ext_vector_type(8)));
typedef float  f32x4  __attribute__((ext_vector_type(4)));

#define MFMA(a, b, c) __builtin_amdgcn_mfma_f32_16x16x32_bf16((a), (b), (c), 0, 0, 0)

// ============ prep: V^T 3-way bf16 split: vth/vtl/vtll[bh][d][t] ============
__global__ __launch_bounds__(NT) void vsplit_kernel(
    const float* __restrict__ v,
    __bf16* __restrict__ vth, __bf16* __restrict__ vtl, __bf16* __restrict__ vtll)
{
    __shared__ float tile[64][65];
    const int tileIdx = blockIdx.x & 15;
    const int bh      = blockIdx.x >> 4;
    const int ti = (tileIdx >> 2) * 64;   // t-origin
    const int tj = (tileIdx & 3) * 64;    // d-origin
    const float* vb = v + (size_t)bh * S * S;

    const int c  = threadIdx.x & 63;
    const int r4 = threadIdx.x >> 6;

    #pragma unroll
    for (int rr = 0; rr < 64; rr += 4)
        tile[rr + r4][c] = vb[(size_t)(ti + rr + r4) * S + tj + c];
    __syncthreads();

    const size_t ob = (size_t)bh * S * S;
    #pragma unroll
    for (int rr = 0; rr < 64; rr += 4) {
        const float x = tile[c][rr + r4];            // v[t=ti+c][d=tj+rr+r4]
        const __bf16 hi = (__bf16)x;
        const float  hf = (float)hi;
        const __bf16 lo = (__bf16)(x - hf);
        const float  lf = (float)lo;
        const __bf16 ll = (__bf16)(x - hf - lf);
        const size_t oi = ob + (size_t)(tj + rr + r4) * S + ti + c;
        vth[oi] = hi; vtl[oi] = lo; vtll[oi] = ll;
    }
}

// ============ QKT: r = (scale*Q) K^T, 3-pass split MFMA -> r_hi/r_lo ============
__global__ __launch_bounds__(NT) void qkt_kernel(
    const float* __restrict__ q, const float* __restrict__ k,
    __bf16* __restrict__ r_hi, __bf16* __restrict__ r_lo, int swz)
{
    __shared__ __align__(16) __bf16 kh[256 * 40];
    __shared__ __align__(16) __bf16 kl[256 * 40];

    const int tid = threadIdx.x;
    const int w = tid >> 6, l = tid & 63, l15 = l & 15, l4 = l >> 4;

    int L = blockIdx.x;
    if (swz) L = (blockIdx.x & 7) * ((int)gridDim.x >> 3) + (blockIdx.x >> 3);
    const int bh = L >> 2;
    const int s0 = (L & 3) << 6;

    const float* qb = q + ((size_t)bh << 16);
    const float* kb = k + ((size_t)bh << 16);

    // ---- Q rows, pre-scaled, hi/lo split (own 16 rows per wave) ----
    bf16x8 qh[8], ql[8];
    {
        const float* qr = qb + (size_t)(s0 + 16 * w + l15) * S;
        #pragma unroll
        for (int kc = 0; kc < 8; ++kc) {
            const float4 f0 = *(const float4*)&qr[kc * 32 + l4 * 8];
            const float4 f1 = *(const float4*)&qr[kc * 32 + l4 * 8 + 4];
            const float xs[8] = {f0.x, f0.y, f0.z, f0.w, f1.x, f1.y, f1.z, f1.w};
            bf16x8 hv, lv;
            #pragma unroll
            for (int e = 0; e < 8; ++e) {
                const float x = xs[e] * SCALE;
                const __bf16 hi = (__bf16)x;
                hv[e] = hi; lv[e] = (__bf16)(x - (float)hi);
            }
            qh[kc] = hv; ql[kc] = lv;
        }
    }

    f32x4 acc[16];
    #pragma unroll
    for (int j = 0; j < 16; ++j) acc[j] = (f32x4){0.f, 0.f, 0.f, 0.f};

    #pragma unroll
    for (int kc = 0; kc < 8; ++kc) {
        #pragma unroll
        for (int pass = 0; pass < 8; ++pass) {
            const int row = pass * 32 + (tid >> 3);
            const int sub = tid & 7;
            const float4 f = *(const float4*)&kb[(size_t)row * S + kc * 32 + sub * 4];
            const float xs[4] = {f.x, f.y, f.z, f.w};
            bf16x4 hv, lv;
            #pragma unroll
            for (int e = 0; e < 4; ++e) {
                const __bf16 hi = (__bf16)xs[e];
                hv[e] = hi; lv[e] = (__bf16)(xs[e] - (float)hi);
            }
            *(bf16x4*)&kh[row * 40 + sub * 4] = hv;
            *(bf16x4*)&kl[row * 40 + sub * 4] = lv;
        }
        __syncthreads();
        #pragma unroll
        for (int j = 0; j < 16; ++j) {
            const int bo = (j * 16 + l15) * 40 + l4 * 8;
            const bf16x8 khf = *(const bf16x8*)&kh[bo];
            const bf16x8 klf = *(const bf16x8*)&kl[bo];
            acc[j] = MFMA(qh[kc], khf, acc[j]);
            acc[j] = MFMA(qh[kc], klf, acc[j]);
            acc[j] = MFMA(ql[kc], khf, acc[j]);
        }
        __syncthreads();
    }

    __bf16* rh_b = r_hi + ((size_t)bh << 16) + (size_t)s0 * S;
    __bf16* rl_b = r_lo + ((size_t)bh << 16) + (size_t)s0 * S;
    #pragma unroll
    for (int j = 0; j < 16; ++j) {
        #pragma unroll
        for (int rr = 0; rr < 4; ++rr) {
            const int row = 16 * w + l4 * 4 + rr;
            const int t   = j * 16 + l15;
            const float rv = acc[j][rr];
            const __bf16 hi = (__bf16)rv;
            rh_b[(size_t)row * S + t] = hi;
            rl_b[(size_t)row * S + t] = (__bf16)(rv - (float)hi);
        }
    }
}

// ============ attn2: (mask + r)@V -> softmax -> P@V ============
__global__ __launch_bounds__(NT) void attn2_kernel(
    const float* __restrict__ mask,
    const __bf16* __restrict__ r_hi, const __bf16* __restrict__ r_lo,
    const __bf16* __restrict__ vth, const __bf16* __restrict__ vtl,
    const __bf16* __restrict__ vtll,
    float* __restrict__ out, int H, int swz)
{
    __shared__ __align__(16) __bf16 pT[64 * 256];   // swizzled P tile (32 KB)

    const int tid = threadIdx.x;
    const int w = tid >> 6, l = tid & 63, l15 = l & 15, l4 = l >> 4;

    int L = blockIdx.x;
    if (swz) L = (blockIdx.x & 7) * ((int)gridDim.x >> 3) + (blockIdx.x >> 3);
    const int bh = L >> 2;
    const int s0 = (L & 3) << 6;
    const int h  = bh % H;

    const size_t hb = (size_t)bh << 16;
    const float* mbase = mask + ((size_t)h << 16);

    const int arow_g = s0 + 16 * w + l15;            // A-frag global row
    const __bf16* rh_p = r_hi + hb + (size_t)arow_g * S;
    const __bf16* rl_p = r_lo + hb + (size_t)arow_g * S;
    const float*  m_p  = mbase + (size_t)arow_g * S;

    // ---- merged sweep: acc = (mask + r) @ V  (6 split passes) ----
    f32x4 acc[16];
    #pragma unroll
    for (int j = 0; j < 16; ++j) acc[j] = (f32x4){0.f, 0.f, 0.f, 0.f};

    for (int tc = 0; tc < 8; ++tc) {
        const int ko = tc * 32 + l4 * 8;
        const bf16x8 rh = *(const bf16x8*)&rh_p[ko];
        const bf16x8 rl = *(const bf16x8*)&rl_p[ko];
        const float4 m0 = *(const float4*)&m_p[ko];
        const float4 m1 = *(const float4*)&m_p[ko + 4];
        bf16x8 mf;
        mf[0] = (__bf16)m0.x; mf[1] = (__bf16)m0.y;
        mf[2] = (__bf16)m0.z; mf[3] = (__bf16)m0.w;
        mf[4] = (__bf16)m1.x; mf[5] = (__bf16)m1.y;
        mf[6] = (__bf16)m1.z; mf[7] = (__bf16)m1.w;
        #pragma unroll
        for (int j = 0; j < 16; ++j) {
            const size_t vo = hb + (size_t)(j * 16 + l15) * S + ko;
            const bf16x8 vh  = *(const bf16x8*)&vth[vo];
            const bf16x8 vl  = *(const bf16x8*)&vtl[vo];
            const bf16x8 vll = *(const bf16x8*)&vtll[vo];
            acc[j] = MFMA(mf, vh,  acc[j]);
            acc[j] = MFMA(mf, vl,  acc[j]);
            acc[j] = MFMA(mf, vll, acc[j]);
            acc[j] = MFMA(rh, vh,  acc[j]);
            acc[j] = MFMA(rh, vl,  acc[j]);
            acc[j] = MFMA(rl, vh,  acc[j]);
        }
    }

    // ---- masked fill + row softmax (in-register, per 16-lane group) ----
    #pragma unroll
    for (int rr = 0; rr < 4; ++rr) {
        const int srow = 16 * w + l4 * 4 + rr;
        const float* mrow = mbase + (size_t)(s0 + srow) * S;
        float mx = -3.4e38f;
        #pragma unroll
        for (int j = 0; j < 16; ++j) {
            const float mval = mrow[j * 16 + l15];
            const float a = (mval == 0.0f) ? -1e9f : acc[j][rr];
            acc[j][rr] = a;
            mx = fmaxf(mx, a);
        }
        #pragma unroll
        for (int off = 1; off < 16; off <<= 1)
            mx = fmaxf(mx, __shfl_xor(mx, off, 64));
        float sm = 0.f;
        #pragma unroll
        for (int j = 0; j < 16; ++j) {
            const float e = __expf(acc[j][rr] - mx);
            acc[j][rr] = e;
            sm += e;
        }
        #pragma unroll
        for (int off = 1; off < 16; off <<= 1)
            sm += __shfl_xor(sm, off, 64);
        const float inv = 1.0f / sm;
        #pragma unroll
        for (int j = 0; j < 16; ++j) {
            const int t = j * 16 + l15;
            pT[((srow << 8) + t) ^ ((srow & 7) << 3)] = (__bf16)(acc[j][rr] * inv);
        }
    }
    __syncthreads();

    // ---- stage 2: out = P @ V  (p*vh + p*vl) ----
    f32x4 acc3[16];
    #pragma unroll
    for (int j = 0; j < 16; ++j) acc3[j] = (f32x4){0.f, 0.f, 0.f, 0.f};

    const int prow = 16 * w + l15;
    for (int tc = 0; tc < 8; ++tc) {
        const int ab = ((prow << 8) + tc * 32 + l4 * 8) ^ ((prow & 7) << 3);
        const bf16x8 pa = *(const bf16x8*)&pT[ab];
        #pragma unroll
        for (int j = 0; j < 16; ++j) {
            const size_t vo = hb + (size_t)(j * 16 + l15) * S + tc * 32 + l4 * 8;
            acc3[j] = MFMA(pa, *(const bf16x8*)&vth[vo], acc3[j]);
            acc3[j] = MFMA(pa, *(const bf16x8*)&vtl[vo], acc3[j]);
        }
    }

    float* ob = out + hb + (size_t)s0 * S;
    #pragma unroll
    for (int j = 0; j < 16; ++j) {
        #pragma unroll
        for (int rr = 0; rr < 4; ++rr)
            ob[(size_t)(16 * w + l4 * 4 + rr) * S + j * 16 + l15] = acc3[j][rr];
    }
}

// ================= fallback: fp32 path (verified round 2) =================
__global__ __launch_bounds__(NT) void transpose_k_kernel(
    const float* __restrict__ k, float* __restrict__ kt)
{
    __shared__ float tile[64][65];
    const int tileIdx = blockIdx.x & 15;
    const int bh      = blockIdx.x >> 4;
    const int ti = (tileIdx >> 2) * 64;
    const int tj = (tileIdx & 3) * 64;
    const float* kb = k  + (size_t)bh * S * S;
    float*      ktb = kt + (size_t)bh * S * S;
    const int c  = threadIdx.x & 63;
    const int r4 = threadIdx.x >> 6;
    #pragma unroll
    for (int rr = 0; rr < 64; rr += 4)
        tile[rr + r4][c] = kb[(size_t)(ti + rr + r4) * S + tj + c];
    __syncthreads();
    #pragma unroll
    for (int rr = 0; rr < 64; rr += 4)
        ktb[(size_t)(tj + rr + r4) * S + ti + c] = tile[c][rr + r4];
}

template <int RPB>
__global__ __launch_bounds__(NT) void fused_attn_rpb(
    const float* __restrict__ q, const float* __restrict__ kt,
    const float* __restrict__ v, const float* __restrict__ mask,
    float* __restrict__ out, int nbh, int H, int swizzle)
{
    __shared__ float qT[S][RPB];
    __shared__ float sT[S][RPB];
    __shared__ float redbuf[4][RPB];

    const int tid = threadIdx.x;
    constexpr int NRB = S / RPB;
    int bh, rb;
    if (swizzle) {
        const int xcd  = blockIdx.x & 7;
        const int slot = blockIdx.x >> 3;
        const int hpx  = nbh >> 3;
        bh = xcd * hpx + (slot % hpx);
        rb = slot / hpx;
    } else {
        bh = blockIdx.x / NRB;
        rb = blockIdx.x % NRB;
    }
    const int h  = bh % H;
    const int s0 = rb * RPB;

    const float* qb  = q    + (size_t)bh * S * S;
    const float* ktb = kt   + (size_t)bh * S * S;
    const float* vb  = v    + (size_t)bh * S * S;
    const float* mb  = mask + (size_t)h  * S * S + (size_t)s0 * S;
    float*       ob  = out  + (size_t)bh * S * S + (size_t)s0 * S;

    #pragma unroll
    for (int si = 0; si < RPB; ++si)
        qT[tid][si] = qb[(size_t)(s0 + si) * S + tid];
    __syncthreads();

    {
        float acc[RPB];
        #pragma unroll
        for (int si = 0; si < RPB; ++si) acc[si] = 0.f;
        #pragma unroll 4
        for (int i = 0; i < S; ++i) {
            const float kv = ktb[(size_t)i * S + tid];
            #pragma unroll
            for (int si4 = 0; si4 < RPB; si4 += 4) {
                const float4 qa = *reinterpret_cast<const float4*>(&qT[i][si4]);
                acc[si4+0] = fmaf(qa.x, kv, acc[si4+0]);
                acc[si4+1] = fmaf(qa.y, kv, acc[si4+1]);
                acc[si4+2] = fmaf(qa.z, kv, acc[si4+2]);
                acc[si4+3] = fmaf(qa.w, kv, acc[si4+3]);
            }
        }
        #pragma unroll
        for (int si4 = 0; si4 < RPB; si4 += 4) {
            float4 t4;
            t4.x = fmaf(acc[si4+0], SCALE, mb[(size_t)(si4+0)*S + tid]);
            t4.y = fmaf(acc[si4+1], SCALE, mb[(size_t)(si4+1)*S + tid]);
            t4.z = fmaf(acc[si4+2], SCALE, mb[(size_t)(si4+2)*S + tid]);
            t4.w = fmaf(acc[si4+3], SCALE, mb[(size_t)(si4+3)*S + tid]);
            *reinterpret_cast<float4*>(&sT[tid][si4]) = t4;
        }
    }
    __syncthreads();

    float a1[RPB];
    #pragma unroll
    for (int si = 0; si < RPB; ++si) a1[si] = 0.f;
    #pragma unroll 2
    for (int t = 0; t < S; ++t) {
        const float vv = vb[(size_t)t * S + tid];
        #pragma unroll
        for (int si4 = 0; si4 < RPB; si4 += 4) {
            const float4 pa = *reinterpret_cast<const float4*>(&sT[t][si4]);
            a1[si4+0] = fmaf(pa.x, vv, a1[si4+0]);
            a1[si4+1] = fmaf(pa.y, vv, a1[si4+1]);
            a1[si4+2] = fmaf(pa.z, vv, a1[si4+2]);
            a1[si4+3] = fmaf(pa.w, vv, a1[si4+3]);
        }
    }
    #pragma unroll
    for (int si = 0; si < RPB; ++si)
        if (mb[(size_t)si * S + tid] == 0.0f) a1[si] = -1e9f;

    const int lane = tid & 63;
    const int wv   = tid >> 6;
    #pragma unroll
    for (int si = 0; si < RPB; ++si) {
        float m = a1[si];
        #pragma unroll
        for (int off = 32; off > 0; off >>= 1)
            m = fmaxf(m, __shfl_down(m, off, 64));
        if (lane == 0) redbuf[wv][si] = m;
    }
    __syncthreads();
    float e[RPB];
    #pragma unroll
    for (int si = 0; si < RPB; ++si) {
        const float m = fmaxf(fmaxf(redbuf[0][si], redbuf[1][si]),
                              fmaxf(redbuf[2][si], redbuf[3][si]));
        e[si] = __expf(a1[si] - m);
    }
    __syncthreads();
    #pragma unroll
    for (int si = 0; si < RPB; ++si) {
        float sm = e[si];
        #pragma unroll
        for (int off = 32; off > 0; off >>= 1)
            sm += __shfl_down(sm, off, 64);
        if (lane == 0) redbuf[wv][si] = sm;
    }
    __syncthreads();
    #pragma unroll
    for (int si4 = 0; si4 < RPB; si4 += 4) {
        float4 t4;
        #pragma unroll
        for (int jj = 0; jj < 4; ++jj) {
            const int si = si4 + jj;
            const float sm = redbuf[0][si] + redbuf[1][si] +
                             redbuf[2][si] + redbuf[3][si];
            (&t4.x)[jj] = e[si] / sm;
        }
        *reinterpret_cast<float4*>(&sT[tid][si4]) = t4;
    }
    __syncthreads();

    float o[RPB];
    #pragma unroll
    for (int si = 0; si < RPB; ++si) o[si] = 0.f;
    #pragma unroll 2
    for (int t = 0; t < S; ++t) {
        const float vv = vb[(size_t)t * S + tid];
        #pragma unroll
        for (int si4 = 0; si4 < RPB; si4 += 4) {
            const float4 pa = *reinterpret_cast<const float4*>(&sT[t][si4]);
            o[si4+0] = fmaf(pa.x, vv, o[si4+0]);
            o[si4+1] = fmaf(pa.y, vv, o[si4+1]);
            o[si4+2] = fmaf(pa.z, vv, o[si4+2]);
            o[si4+3] = fmaf(pa.w, vv, o[si4+3]);
        }
    }
    #pragma unroll
    for (int si = 0; si < RPB; ++si)
        ob[(size_t)si * S + tid] = o[si];
}

extern "C" void kernel_launch(void* const* d_in, const int* in_sizes, int n_in,
                              void* d_out, int out_size, void* d_ws, size_t ws_size,
                              hipStream_t stream) {
    const float* q    = (const float*)d_in[0];
    const float* k    = (const float*)d_in[1];
    const float* v    = (const float*)d_in[2];
    const float* mask = (const float*)d_in[3];
    float* out = (float*)d_out;

    const int nbh = in_sizes[0] / (S * S);   // B*H
    const int H   = in_sizes[3] / (S * S);   // heads
    const size_t he = (size_t)nbh * S * S;
    const size_t need = he * sizeof(__bf16) * 5;   // vth,vtl,vtll,r_hi,r_lo
    const size_t kt_bytes = he * sizeof(float);

    if (ws_size >= need) {
        __bf16* vth  = (__bf16*)d_ws;
        __bf16* vtl  = vth + he;
        __bf16* vtll = vtl + he;
        __bf16* rhi  = vtll + he;
        __bf16* rlo  = rhi + he;
        const int nblk = nbh * 4;
        const int swz = (nblk % 8 == 0) ? 1 : 0;
        vsplit_kernel<<<dim3(nbh * 16), NT, 0, stream>>>(v, vth, vtl, vtll);
        qkt_kernel<<<dim3(nblk), NT, 0, stream>>>(q, k, rhi, rlo, swz);
        attn2_kernel<<<dim3(nblk), NT, 0, stream>>>(
            mask, rhi, rlo, vth, vtl, vtll, out, H, swz);
    } else if (ws_size >= kt_bytes) {
        float* kt = (float*)d_ws;
        transpose_k_kernel<<<dim3(nbh * 16), NT, 0, stream>>>(k, kt);
        constexpr int RPB = 16;
        const int grid = nbh * (S / RPB);
        const int swz = (nbh % 8 == 0) ? 1 : 0;
        fused_attn_rpb<RPB><<<dim3(grid), NT, 0, stream>>>(
            q, kt, v, mask, out, nbh, H, swz);
    }
}